// Round 5
// baseline (203.736 us; speedup 1.0000x reference)
//
#include <hip/hip_runtime.h>
#include <hip/hip_bf16.h>

// QLinear: per-row absmax int8 quant -> int8 GEMM (MFMA) -> fused dequant.
// M=8192, K=4096, N=4096 (derived from in_sizes at launch).

using int32x4 = __attribute__((ext_vector_type(4))) int;

#define QMAXF 127.0f

// ---------------------------------------------------------------------------
// Kernel 0: weight repack (int32-marshalled int8 -> packed int8). Self-detects
// encoding by probing the first 16 words.
// ---------------------------------------------------------------------------
__global__ __launch_bounds__(256) void repack_weights(
    const int* __restrict__ w, signed char* __restrict__ w8, int total)
{
    bool is32 = true;
#pragma unroll
    for (int i = 0; i < 16; ++i) {
        int v = w[i];
        is32 = is32 && (v >= -127 && v <= 127);
    }

    const int t = blockIdx.x * blockDim.x + threadIdx.x;
    const int nth = gridDim.x * blockDim.x;
    const int chunks = total / 16;

    if (is32) {
        for (int c = t; c < chunks; c += nth) {
            const int32x4* src = reinterpret_cast<const int32x4*>(w + (size_t)c * 16);
            int32x4 a0 = src[0], a1 = src[1], a2 = src[2], a3 = src[3];
            int32x4 o;
            o[0] = (a0[0] & 0xff) | ((a0[1] & 0xff) << 8) | ((a0[2] & 0xff) << 16) | ((a0[3] & 0xff) << 24);
            o[1] = (a1[0] & 0xff) | ((a1[1] & 0xff) << 8) | ((a1[2] & 0xff) << 16) | ((a1[3] & 0xff) << 24);
            o[2] = (a2[0] & 0xff) | ((a2[1] & 0xff) << 8) | ((a2[2] & 0xff) << 16) | ((a2[3] & 0xff) << 24);
            o[3] = (a3[0] & 0xff) | ((a3[1] & 0xff) << 8) | ((a3[2] & 0xff) << 16) | ((a3[3] & 0xff) << 24);
            reinterpret_cast<int32x4*>(w8)[c] = o;
        }
    } else {
        const int32x4* src = reinterpret_cast<const int32x4*>(w);
        int32x4* dst = reinterpret_cast<int32x4*>(w8);
        for (int c = t; c < chunks; c += nth) dst[c] = src[c];
    }
}

// ---------------------------------------------------------------------------
// Kernel 1: per-row absmax quantization. One block (256 thr) per row, K=4096.
// ---------------------------------------------------------------------------
__global__ __launch_bounds__(256) void quant_rows(
    const float* __restrict__ x, signed char* __restrict__ q,
    float* __restrict__ scale, int K)
{
    const int row = blockIdx.x;
    const int t = threadIdx.x;
    const float4* xr = reinterpret_cast<const float4*>(x + (size_t)row * K);

    float4 v[4];
    float m = 0.f;
#pragma unroll
    for (int i = 0; i < 4; ++i) {
        v[i] = xr[t + i * 256];
        m = fmaxf(m, fmaxf(fmaxf(fabsf(v[i].x), fabsf(v[i].y)),
                           fmaxf(fabsf(v[i].z), fabsf(v[i].w))));
    }
#pragma unroll
    for (int off = 32; off >= 1; off >>= 1)
        m = fmaxf(m, __shfl_xor(m, off, 64));
    __shared__ float wmax[4];
    const int wave = t >> 6;
    if ((t & 63) == 0) wmax[wave] = m;
    __syncthreads();
    m = fmaxf(fmaxf(wmax[0], wmax[1]), fmaxf(wmax[2], wmax[3]));

    const float s   = m / QMAXF;
    const float inv = (m > 0.f) ? (QMAXF / m) : 0.f;
    if (t == 0) scale[row] = s;

    int* qr = reinterpret_cast<int*>(q + (size_t)row * K);
#pragma unroll
    for (int i = 0; i < 4; ++i) {
        const float* f = reinterpret_cast<const float*>(&v[i]);
        unsigned int packed = 0;
#pragma unroll
        for (int j = 0; j < 4; ++j) {
            int qi = __float2int_rn(f[j] * inv);
            qi = qi > 127 ? 127 : (qi < -127 ? -127 : qi);
            packed |= ((unsigned int)(qi & 0xff)) << (8 * j);
        }
        qr[t + i * 256] = (int)packed;
    }
}

// ---------------------------------------------------------------------------
// Kernel 2: int8 GEMM, 256x256 tile, 8 waves (2Mx4N), K-step = 64 bytes.
// 4-buffer LDS, stage-ahead 4 (counted vmcnt, T4) + REGISTER double-buffered
// fragments (T14 on the LDS->reg leg): tile t's 32 MFMAs read only registers
// while tile t+1's 12 ds_read_b128 fill the alternate register set, so the
// post-barrier LDS burst overlaps the MFMA block instead of preceding it.
//
// Fragment-order LDS (zero bank conflicts): 1 KB frag-tile fi holds the MFMA
// operand for rows [fi*16,fi*16+16) x 64 k-bytes, lane-linear; per-lane
// global address is row fi*16+(l&15), kcol (l>>4)*16, so every ds_read_b128
// at base + lane*16 is fully linear.
//
// Hazard ledger (per steady iter tt):
//  - reg-prefetch of tile tt+1 reads buf (tt+1)&3: all-waves DMA landed is
//    guaranteed by each wave's vmcnt(8) BEFORE the end-of-iter-(tt-1) barrier
//    (in flight there: tiles tt+1,tt+2,tt+3 = 12 loads -> vmcnt(8) = tt+1 in).
//  - stage of tile tt+4 rewrites buf tt&3: its readers (reg-prefetch of tile
//    tt during iter tt-1) are lgkmcnt(0)-drained before that same barrier.
//  - MFMAs read only regs; compiler chains lgkm deps across iters.
// ---------------------------------------------------------------------------
#define BM 256
#define BN 256
#define BKB 64
#define NBUF 4

__device__ __forceinline__ void async_copy16(const void* g, void* lds) {
    __builtin_amdgcn_global_load_lds(
        (const __attribute__((address_space(1))) void*)g,
        (__attribute__((address_space(3))) void*)lds, 16, 0, 0);
}

__global__ __launch_bounds__(512, 2) void gemm_i8_dequant_rp(
    const signed char* __restrict__ A,   // [M,K] qinp
    const signed char* __restrict__ B,   // [N,K] qweight (packed int8)
    const float* __restrict__ a_scale,   // [M]
    const float* __restrict__ wparams,   // [N]
    const float* __restrict__ bias,      // [N]
    float* __restrict__ out,             // [M,N]
    int M, int N, int K)
{
    __shared__ __align__(16) signed char lds[NBUF * 32768];   // 128 KiB

    const int t    = threadIdx.x;
    const int lane = t & 63;
    const int wave = t >> 6;           // 0..7
    const int wr   = wave >> 2;        // 0..1 (M half)
    const int wc   = wave & 3;         // 0..3 (N quarter)

    // T1: XCD-aware bijective swizzle (nwg % 8 == 0)
    const int nwg = gridDim.x;
    const int cpx = nwg >> 3;
    const int swz = (blockIdx.x & 7) * cpx + (blockIdx.x >> 3);
    const int nbx = N / BN;
    const int rowBase = (swz / nbx) * BM;
    const int colBase = (swz % nbx) * BN;

    const int r15 = lane & 15;
    const int ksl = lane >> 4;

    int32x4 acc[8][4] = {};
    const int NT = K / BKB;            // 64

    const signed char* gA0 = A + (size_t)(rowBase + wave * 16 + r15)       * K + ksl * 16;
    const signed char* gA1 = A + (size_t)(rowBase + (8 + wave) * 16 + r15) * K + ksl * 16;
    const signed char* gB0 = B + (size_t)(colBase + wave * 16 + r15)       * K + ksl * 16;
    const signed char* gB1 = B + (size_t)(colBase + (8 + wave) * 16 + r15) * K + ksl * 16;

    auto stageA = [&](int tile) {
        signed char* L = lds + (tile & (NBUF - 1)) * 32768;
        const size_t kt = (size_t)tile * BKB;
        async_copy16(gA0 + kt, L + wave * 1024);
        async_copy16(gA1 + kt, L + (8 + wave) * 1024);
    };
    auto stageB = [&](int tile) {
        signed char* L = lds + (tile & (NBUF - 1)) * 32768 + 16384;
        const size_t kt = (size_t)tile * BKB;
        async_copy16(gB0 + kt, L + wave * 1024);
        async_copy16(gB1 + kt, L + (8 + wave) * 1024);
    };
    auto ldFrags = [&](int tile, int32x4 (&fa)[8], int32x4 (&fb)[4]) {
        const signed char* Ab = lds + (tile & (NBUF - 1)) * 32768;
        const signed char* Bb = Ab + 16384;
#pragma unroll
        for (int mm = 0; mm < 8; ++mm)
            fa[mm] = *reinterpret_cast<const int32x4*>(
                Ab + (wr * 8 + mm) * 1024 + lane * 16);
#pragma unroll
        for (int nn = 0; nn < 4; ++nn)
            fb[nn] = *reinterpret_cast<const int32x4*>(
                Bb + (wc * 4 + nn) * 1024 + lane * 16);
    };
    auto mfmaAll = [&](const int32x4 (&fa)[8], const int32x4 (&fb)[4]) {
        __builtin_amdgcn_s_setprio(1);
#pragma unroll
        for (int mm = 0; mm < 8; ++mm)
#pragma unroll
            for (int nn = 0; nn < 4; ++nn)
                acc[mm][nn] = __builtin_amdgcn_mfma_i32_16x16x64_i8(
                    fa[mm], fb[nn], acc[mm][nn], 0, 0, 0);
        __builtin_amdgcn_s_setprio(0);
    };

    int32x4 rA0[8], rB0[4], rA1[8], rB1[4];

    // ---- prologue: stage tiles 0..3 (16 loads) ----
    stageA(0); stageB(0);
    stageA(1); stageB(1);
    stageA(2); stageB(2);
    stageA(3); stageB(3);
    asm volatile("s_waitcnt vmcnt(8)" ::: "memory");   // tiles 0,1 landed (own)
    __builtin_amdgcn_s_barrier();                      // -> all waves' 0,1 in
    ldFrags(0, rA0, rB0);
    asm volatile("s_waitcnt lgkmcnt(0)" ::: "memory"); // buf0 reads drained
    __builtin_amdgcn_s_barrier();

    // ---- steady: tt = 0..NT-5, unrolled by 2 for reg ping-pong ----
    for (int tt = 0; tt < NT - 4; tt += 2) {
        stageA(tt + 4);
        ldFrags(tt + 1, rA1, rB1);
        stageB(tt + 4);
        mfmaAll(rA0, rB0);
        asm volatile("s_waitcnt vmcnt(8) lgkmcnt(0)" ::: "memory");
        __builtin_amdgcn_s_barrier();

        stageA(tt + 5);
        ldFrags(tt + 2, rA0, rB0);
        stageB(tt + 5);
        mfmaAll(rA1, rB1);
        asm volatile("s_waitcnt vmcnt(8) lgkmcnt(0)" ::: "memory");
        __builtin_amdgcn_s_barrier();
    }

    // ---- tail: tiles NT-4..NT-1 (parities 0,1,0,1) ----
    ldFrags(NT - 3, rA1, rB1);
    mfmaAll(rA0, rB0);
    asm volatile("s_waitcnt vmcnt(4) lgkmcnt(0)" ::: "memory");
    __builtin_amdgcn_s_barrier();
    ldFrags(NT - 2, rA0, rB0);
    mfmaAll(rA1, rB1);
    asm volatile("s_waitcnt vmcnt(0) lgkmcnt(0)" ::: "memory");
    __builtin_amdgcn_s_barrier();
    ldFrags(NT - 1, rA1, rB1);
    mfmaAll(rA0, rB0);
    mfmaAll(rA1, rB1);

    // ---- epilogue: dequant + bias. C/D map: col=lane&15, row=(lane>>4)*4+r
#pragma unroll
    for (int mm = 0; mm < 8; ++mm) {
        const int rb = rowBase + wr * 128 + mm * 16 + ksl * 4;
        float asc[4];
#pragma unroll
        for (int r = 0; r < 4; ++r) asc[r] = a_scale[rb + r];
#pragma unroll
        for (int nn = 0; nn < 4; ++nn) {
            const int col = colBase + wc * 64 + nn * 16 + r15;
            const float wp = wparams[col];
            const float bs = bias[col];
#pragma unroll
            for (int r = 0; r < 4; ++r) {
                out[(size_t)(rb + r) * N + col] =
                    (float)acc[mm][nn][r] * asc[r] * wp + bs;
            }
        }
    }
}

// ---------------------------------------------------------------------------
extern "C" void kernel_launch(void* const* d_in, const int* in_sizes, int n_in,
                              void* d_out, int out_size, void* d_ws, size_t ws_size,
                              hipStream_t stream) {
    const float* inp     = (const float*)d_in[0];
    const int*   qw_raw  = (const int*)d_in[1];
    const float* wparams = (const float*)d_in[2];
    const float* bias    = (const float*)d_in[3];
    float*       out     = (float*)d_out;

    const int N = in_sizes[2];             // 4096
    const int K = in_sizes[1] / N;         // 4096
    const int M = in_sizes[0] / K;         // 8192

    // workspace: qinp [M*K B] | a_scale [M*4 B, 256-pad] | w8 [N*K B]
    signed char* qinp    = (signed char*)d_ws;
    float*       a_scale = (float*)((char*)d_ws + (size_t)M * K);
    size_t off_w8 = (size_t)M * K + (((size_t)M * sizeof(float) + 255) & ~(size_t)255);
    signed char* w8      = (signed char*)((char*)d_ws + off_w8);

    repack_weights<<<2048, 256, 0, stream>>>(qw_raw, w8, N * K);
    quant_rows<<<M, 256, 0, stream>>>(inp, qinp, a_scale, K);

    const int nwg = (M / BM) * (N / BN);   // 32*16 = 512, %8 == 0
    gemm_i8_dequant_rp<<<nwg, 512, 0, stream>>>(
        qinp, w8, a_scale, wparams, bias, out, M, N, K);
}

// Round 7
// 203.158 us; speedup vs baseline: 1.0028x; 1.0028x over previous
//
#include <hip/hip_runtime.h>
#include <hip/hip_bf16.h>

// QLinear: per-row absmax int8 quant -> int8 GEMM (MFMA) -> fused dequant.
// M=8192, K=4096, N=4096 (derived from in_sizes at launch).

using int32x4 = __attribute__((ext_vector_type(4))) int;

#define QMAXF 127.0f

// ---------------------------------------------------------------------------
// Kernel 0: weight repack (int32-marshalled int8 -> packed int8).
// ---------------------------------------------------------------------------
__global__ __launch_bounds__(256) void repack_weights(
    const int* __restrict__ w, signed char* __restrict__ w8, int total)
{
    bool is32 = true;
#pragma unroll
    for (int i = 0; i < 16; ++i) {
        int v = w[i];
        is32 = is32 && (v >= -127 && v <= 127);
    }

    const int t = blockIdx.x * blockDim.x + threadIdx.x;
    const int nth = gridDim.x * blockDim.x;
    const int chunks = total / 16;

    if (is32) {
        for (int c = t; c < chunks; c += nth) {
            const int32x4* src = reinterpret_cast<const int32x4*>(w + (size_t)c * 16);
            int32x4 a0 = src[0], a1 = src[1], a2 = src[2], a3 = src[3];
            int32x4 o;
            o[0] = (a0[0] & 0xff) | ((a0[1] & 0xff) << 8) | ((a0[2] & 0xff) << 16) | ((a0[3] & 0xff) << 24);
            o[1] = (a1[0] & 0xff) | ((a1[1] & 0xff) << 8) | ((a1[2] & 0xff) << 16) | ((a1[3] & 0xff) << 24);
            o[2] = (a2[0] & 0xff) | ((a2[1] & 0xff) << 8) | ((a2[2] & 0xff) << 16) | ((a2[3] & 0xff) << 24);
            o[3] = (a3[0] & 0xff) | ((a3[1] & 0xff) << 8) | ((a3[2] & 0xff) << 16) | ((a3[3] & 0xff) << 24);
            reinterpret_cast<int32x4*>(w8)[c] = o;
        }
    } else {
        const int32x4* src = reinterpret_cast<const int32x4*>(w);
        int32x4* dst = reinterpret_cast<int32x4*>(w8);
        for (int c = t; c < chunks; c += nth) dst[c] = src[c];
    }
}

// ---------------------------------------------------------------------------
// Kernel 1: per-row absmax quantization. One block (256 thr) per row, K=4096.
// ---------------------------------------------------------------------------
__global__ __launch_bounds__(256) void quant_rows(
    const float* __restrict__ x, signed char* __restrict__ q,
    float* __restrict__ scale, int K)
{
    const int row = blockIdx.x;
    const int t = threadIdx.x;
    const float4* xr = reinterpret_cast<const float4*>(x + (size_t)row * K);

    float4 v[4];
    float m = 0.f;
#pragma unroll
    for (int i = 0; i < 4; ++i) {
        v[i] = xr[t + i * 256];
        m = fmaxf(m, fmaxf(fmaxf(fabsf(v[i].x), fabsf(v[i].y)),
                           fmaxf(fabsf(v[i].z), fabsf(v[i].w))));
    }
#pragma unroll
    for (int off = 32; off >= 1; off >>= 1)
        m = fmaxf(m, __shfl_xor(m, off, 64));
    __shared__ float wmax[4];
    const int wave = t >> 6;
    if ((t & 63) == 0) wmax[wave] = m;
    __syncthreads();
    m = fmaxf(fmaxf(wmax[0], wmax[1]), fmaxf(wmax[2], wmax[3]));

    const float s   = m / QMAXF;
    const float inv = (m > 0.f) ? (QMAXF / m) : 0.f;
    if (t == 0) scale[row] = s;

    int* qr = reinterpret_cast<int*>(q + (size_t)row * K);
#pragma unroll
    for (int i = 0; i < 4; ++i) {
        const float* f = reinterpret_cast<const float*>(&v[i]);
        unsigned int packed = 0;
#pragma unroll
        for (int j = 0; j < 4; ++j) {
            int qi = __float2int_rn(f[j] * inv);
            qi = qi > 127 ? 127 : (qi < -127 ? -127 : qi);
            packed |= ((unsigned int)(qi & 0xff)) << (8 * j);
        }
        qr[t + i * 256] = (int)packed;
    }
}

// ---------------------------------------------------------------------------
// Kernel 2: int8 GEMM, 256x256 tile, 8 waves (2Mx4N), K-step = 64 bytes.
// Fine-phase schedule (m201 geometry): per K-tile, TWO phases, each
// {ds_read subtile || issue 2 global_load_lds -> BARRIER -> lgkmcnt(0) ->
//  setprio(1) 16 MFMA setprio(0) -> BARRIER}.
// Counted vmcnt only at tile end (T4): vmcnt(8) steady, 4/0 in tails.
//
// RACE FIX (round 6 -> 7): raw s_barrier is NOT a compiler memory fence, so
// LLVM could hoist the next segment's global_load_lds above the barrier into
// a segment where another wave still has in-flight ds_reads of the target
// buffer (cross-wave WAR), and could sink a stage below the counted vmcnt
// (ledger corruption). Every barrier is now two-side fenced with
// sched_barrier(0) + empty asm memory clobber -- zero runtime instructions,
// pins all memory ops into their written segments.
//
// Fragment-order LDS (zero bank conflicts): 1 KB frag-tile fi holds the MFMA
// operand for rows [fi*16,fi*16+16) x 64 k-bytes, lane-linear; per-lane
// global address is row fi*16+(l&15), kcol (l>>4)*16, so every ds_read_b128
// at base + lane*16 is fully linear.
//
// Hazard ledger (steady iter tt, buffers (x)&3):
//  - ph1 vmcnt(8): own outstanding = tiles tt+1,tt+2,tt+3 (4 loads each) = 12;
//    vmcnt(8) retires the 4 oldest = tile tt+1; following barrier makes it
//    all-waves -> iter tt+1 ph0 may read buf (tt+1)&3.
//  - stage of tile tt+3 overwrites buf (tt-1)&3: all readers (iter tt-1) are
//    lgkmcnt(0)-drained before iter tt-1's final barrier, which (now
//    enforceably) precedes this iter's stage issues.
// ---------------------------------------------------------------------------
#define BM 256
#define BN 256
#define BKB 64
#define NBUF 4

__device__ __forceinline__ void async_copy16(const void* g, void* lds) {
    __builtin_amdgcn_global_load_lds(
        (const __attribute__((address_space(1))) void*)g,
        (__attribute__((address_space(3))) void*)lds, 16, 0, 0);
}

// fenced barrier: no memory op may move across, in either direction
#define BAR do {                                          \
    __builtin_amdgcn_sched_barrier(0);                    \
    asm volatile("" ::: "memory");                        \
    __builtin_amdgcn_s_barrier();                         \
    asm volatile("" ::: "memory");                        \
    __builtin_amdgcn_sched_barrier(0);                    \
} while (0)

#define LGKM0 asm volatile("s_waitcnt lgkmcnt(0)" ::: "memory")
#define VM8   asm volatile("s_waitcnt vmcnt(8)" ::: "memory")
#define VM4   asm volatile("s_waitcnt vmcnt(4)" ::: "memory")
#define VM0   asm volatile("s_waitcnt vmcnt(0)" ::: "memory")
#define VMN   ((void)0)

#define MFMA16(ACCB, AF, FB)                                                 \
    __builtin_amdgcn_s_setprio(1);                                           \
    _Pragma("unroll")                                                        \
    for (int mm = 0; mm < 4; ++mm)                                           \
        _Pragma("unroll")                                                    \
        for (int nn = 0; nn < 4; ++nn)                                       \
            acc[(ACCB) + mm][nn] = __builtin_amdgcn_mfma_i32_16x16x64_i8(    \
                AF[mm], FB[nn], acc[(ACCB) + mm][nn], 0, 0, 0);              \
    __builtin_amdgcn_s_setprio(0);

#define TILE_ITER(T, DOSTAGE, VMASM)                                         \
  {                                                                          \
    const signed char* Ab = lds + ((T) & 3) * 32768 + wr * 8192 + lane * 16; \
    const signed char* Bb = lds + ((T) & 3) * 32768 + 16384 + wc * 4096 + lane * 16; \
    signed char* Ln = lds + (((T) + 3) & 3) * 32768;                         \
    const size_t _kt = (size_t)((T) + 3) * BKB;                              \
    int32x4 fb[4], af[4];                                                    \
    /* ---- phase 0: B-frags + A-frags 0..3 || stage A of tile T+3 ---- */   \
    fb[0] = *(const int32x4*)(Bb);                                           \
    fb[1] = *(const int32x4*)(Bb + 1024);                                    \
    fb[2] = *(const int32x4*)(Bb + 2048);                                    \
    fb[3] = *(const int32x4*)(Bb + 3072);                                    \
    af[0] = *(const int32x4*)(Ab);                                           \
    af[1] = *(const int32x4*)(Ab + 1024);                                    \
    af[2] = *(const int32x4*)(Ab + 2048);                                    \
    af[3] = *(const int32x4*)(Ab + 3072);                                    \
    if (DOSTAGE) {                                                           \
        async_copy16(gA0 + _kt, Ln + wave * 1024);                           \
        async_copy16(gA1 + _kt, Ln + (8 + wave) * 1024);                     \
    }                                                                        \
    BAR; LGKM0;                                                              \
    MFMA16(0, af, fb);                                                       \
    BAR;                                                                     \
    /* ---- phase 1: A-frags 4..7 || stage B of tile T+3 ---- */             \
    af[0] = *(const int32x4*)(Ab + 4096);                                    \
    af[1] = *(const int32x4*)(Ab + 5120);                                    \
    af[2] = *(const int32x4*)(Ab + 6144);                                    \
    af[3] = *(const int32x4*)(Ab + 7168);                                    \
    if (DOSTAGE) {                                                           \
        async_copy16(gB0 + _kt, Ln + 16384 + wave * 1024);                   \
        async_copy16(gB1 + _kt, Ln + 16384 + (8 + wave) * 1024);             \
    }                                                                        \
    VMASM;                                                                   \
    BAR; LGKM0;                                                              \
    MFMA16(4, af, fb);                                                       \
    BAR;                                                                     \
  }

__global__ __launch_bounds__(512, 2) void gemm_i8_dequant_ph(
    const signed char* __restrict__ A,   // [M,K] qinp
    const signed char* __restrict__ B,   // [N,K] qweight (packed int8)
    const float* __restrict__ a_scale,   // [M]
    const float* __restrict__ wparams,   // [N]
    const float* __restrict__ bias,      // [N]
    float* __restrict__ out,             // [M,N]
    int M, int N, int K)
{
    __shared__ __align__(16) signed char lds[NBUF * 32768];   // 128 KiB

    const int t    = threadIdx.x;
    const int lane = t & 63;
    const int wave = t >> 6;           // 0..7
    const int wr   = wave >> 2;        // 0..1 (M half)
    const int wc   = wave & 3;         // 0..3 (N quarter)

    // T1: XCD-aware bijective swizzle (nwg % 8 == 0)
    const int nwg = gridDim.x;
    const int cpx = nwg >> 3;
    const int swz = (blockIdx.x & 7) * cpx + (blockIdx.x >> 3);
    const int nbx = N / BN;
    const int rowBase = (swz / nbx) * BM;
    const int colBase = (swz % nbx) * BN;

    const int r15 = lane & 15;
    const int ksl = lane >> 4;

    int32x4 acc[8][4] = {};
    const int NT = K / BKB;            // 64

    const signed char* gA0 = A + (size_t)(rowBase + wave * 16 + r15)       * K + ksl * 16;
    const signed char* gA1 = A + (size_t)(rowBase + (8 + wave) * 16 + r15) * K + ksl * 16;
    const signed char* gB0 = B + (size_t)(colBase + wave * 16 + r15)       * K + ksl * 16;
    const signed char* gB1 = B + (size_t)(colBase + (8 + wave) * 16 + r15) * K + ksl * 16;

    // ---- prologue: stage tiles 0,1,2 (12 loads/wave) ----
#pragma unroll
    for (int p = 0; p < 3; ++p) {
        signed char* L = lds + p * 32768;
        const size_t kt = (size_t)p * BKB;
        async_copy16(gA0 + kt, L + wave * 1024);
        async_copy16(gA1 + kt, L + (8 + wave) * 1024);
        async_copy16(gB0 + kt, L + 16384 + wave * 1024);
        async_copy16(gB1 + kt, L + 16384 + (8 + wave) * 1024);
    }
    VM8;                               // own tile-0 loads landed
    BAR;                               // -> all waves' tile-0 loads landed

    // ---- steady: tiles 0 .. NT-4 stage tile T+3, vmcnt(8) ----
    for (int tt = 0; tt < NT - 3; ++tt)
        TILE_ITER(tt, true, VM8);

    // ---- tails ----
    TILE_ITER(NT - 3, false, VM4);
    TILE_ITER(NT - 2, false, VM0);
    TILE_ITER(NT - 1, false, VMN);

    // ---- epilogue: dequant + bias. C/D map: col=lane&15, row=(lane>>4)*4+r
#pragma unroll
    for (int mm = 0; mm < 8; ++mm) {
        const int rb = rowBase + wr * 128 + mm * 16 + ksl * 4;
        float asc[4];
#pragma unroll
        for (int r = 0; r < 4; ++r) asc[r] = a_scale[rb + r];
#pragma unroll
        for (int nn = 0; nn < 4; ++nn) {
            const int col = colBase + wc * 64 + nn * 16 + r15;
            const float wp = wparams[col];
            const float bs = bias[col];
#pragma unroll
            for (int r = 0; r < 4; ++r) {
                out[(size_t)(rb + r) * N + col] =
                    (float)acc[mm][nn][r] * asc[r] * wp + bs;
            }
        }
    }
}

// ---------------------------------------------------------------------------
extern "C" void kernel_launch(void* const* d_in, const int* in_sizes, int n_in,
                              void* d_out, int out_size, void* d_ws, size_t ws_size,
                              hipStream_t stream) {
    const float* inp     = (const float*)d_in[0];
    const int*   qw_raw  = (const int*)d_in[1];
    const float* wparams = (const float*)d_in[2];
    const float* bias    = (const float*)d_in[3];
    float*       out     = (float*)d_out;

    const int N = in_sizes[2];             // 4096
    const int K = in_sizes[1] / N;         // 4096
    const int M = in_sizes[0] / K;         // 8192

    // workspace: qinp [M*K B] | a_scale [M*4 B, 256-pad] | w8 [N*K B]
    signed char* qinp    = (signed char*)d_ws;
    float*       a_scale = (float*)((char*)d_ws + (size_t)M * K);
    size_t off_w8 = (size_t)M * K + (((size_t)M * sizeof(float) + 255) & ~(size_t)255);
    signed char* w8      = (signed char*)((char*)d_ws + off_w8);

    repack_weights<<<2048, 256, 0, stream>>>(qw_raw, w8, N * K);
    quant_rows<<<M, 256, 0, stream>>>(inp, qinp, a_scale, K);

    const int nwg = (M / BM) * (N / BN);   // 32*16 = 512, %8 == 0
    gemm_i8_dequant_ph<<<nwg, 512, 0, stream>>>(
        qinp, w8, a_scale, wparams, bias, out, M, N, K);
}